// Round 1
// baseline (1190.989 us; speedup 1.0000x reference)
//
#include <hip/hip_runtime.h>
#include <cmath>

#define BB 16
#define NN 1024
#define KK1 205
#define KK2 42
#define CAP 96
#define THREADS 256

// virtual-block counts per phase
#define VB_DEG    (BB * NN / 4)        // 4096
#define VB_SPMM   (BB * NN / 8)        // 2048
#define VB_TOPK   BB                   // 16
#define VB_A1     (BB * 52)            // 832
#define VB_DENSE1 (BB * KK1)           // 3280
#define VB_A2     (BB * KK2)           // 672
#define VB_DENSE2 (BB * KK2)           // 672
#define VB_XU1    (BB * KK1 * 32 / 256) // 410
#define VB_XU0    (BB * NN * 32 / 256)  // 2048
#define VB_BN     128
#define VB_MLP    (BB * NN / 256)      // 64

struct Params {
  const float *x, *adj, *Wd0, *bd0, *Wd1, *bd1, *Wd2, *bd2;
  const float *Wu0, *bu0, *Wu1, *bu1, *p1, *p2;
  const float *gamma, *beta, *W1, *b1, *W2, *b2, *W3, *b3;
  float *out;
  float *dis0; int *ncnt; int *nbr; unsigned long long *mask;
  float *dxw, *h0, *score1; int *perm1; float *vals1; int *inv1;
  float *A1, *dis1, *t1, *h1, *score2; int *perm2; float *vals2; int *inv2;
  float *A2, *dis2, *t2, *h2, *hu0, *hfin, *pacc;
  unsigned *bar;
};

union SMem {
  struct { unsigned long long smT[16 * KK1]; int sp[KK1]; } a1;   // ~26.4 KB (max)
  unsigned long long skey[1024];                                   // 8 KB
  float ls[8][32];
  struct { float ls[8][32], lq[8][32]; } bn;
  struct { float gsum[8]; float ds2; } a2;
  struct { float W1s[1024], W2s[1024], W3s[128];
           float b1s[32], b2s[32], b3s[4], scale[32], shift[32]; } mlp;
};

// ---------------- software global barrier (agent scope) --------------------
__device__ __forceinline__ void gsync(unsigned* bar, int phase, int nb) {
  __threadfence();                       // release: drain + write back dirty L2
  __syncthreads();
  if (threadIdx.x == 0) {
    __hip_atomic_fetch_add(&bar[phase], 1u, __ATOMIC_ACQ_REL, __HIP_MEMORY_SCOPE_AGENT);
    unsigned cur;
    do {
      __builtin_amdgcn_s_sleep(2);
      cur = __hip_atomic_load(&bar[phase], __ATOMIC_ACQUIRE, __HIP_MEMORY_SCOPE_AGENT);
    } while (cur < (unsigned)nb);
  }
  __syncthreads();
  __threadfence();                       // acquire: invalidate for fresh reads
}

// ---------------- phase 1: degree + bitmask + CSR + fused x@Wd0 ------------
__device__ void p_deg(const Params& P, int vb) {
  int row = vb * 4 + (threadIdx.x >> 6);
  int lane = threadIdx.x & 63;
  const float* ar = P.adj + (size_t)row * NN;
  float v[16];
#pragma unroll
  for (int c = 0; c < 16; ++c) v[c] = ar[c * 64 + lane];   // 16 loads in flight
  int base = 0;
  int* nr = P.nbr + (size_t)row * CAP;
#pragma unroll
  for (int c = 0; c < 16; ++c) {
    unsigned long long m = __ballot(v[c] != 0.0f);
    if (lane == c) P.mask[(size_t)row * 16 + c] = m;
    if (v[c] != 0.0f) {
      int pos = base + __popcll(m & ((1ull << lane) - 1ull));
      if (pos < CAP) nr[pos] = c * 64 + lane;
    }
    base += __popcll(m);
  }
  float dis = rsqrtf((float)base + 2.0f);
  if (lane == 0) {
    P.ncnt[row] = base < CAP ? base : CAP;
    P.dis0[row] = dis;
  }
  if (lane < 32) {
    float x0 = P.x[row * 3], x1 = P.x[row * 3 + 1], x2 = P.x[row * 3 + 2];
    float s = x0 * P.Wd0[lane] + x1 * P.Wd0[32 + lane] + x2 * P.Wd0[64 + lane];
    P.dxw[(size_t)row * 32 + lane] = s * dis;
  }
}

// ---------------- sparse GCN apply (+optional fused pool score) ------------
template<bool RELU, bool SCORE>
__device__ void p_spmm(const float* __restrict__ dxw, const float* __restrict__ dis,
                       const int* __restrict__ ncnt, const int* __restrict__ nbr,
                       const float* __restrict__ bias, float* __restrict__ out,
                       float* __restrict__ score, const float* __restrict__ p, int vb) {
  int tid = threadIdx.x;
  int g = tid >> 5, f = tid & 31;
  int node = vb * 8 + g;
  int b = node >> 10;
  int cnt = ncnt[node];
  const int* lst = nbr + (size_t)node * CAP;
  const float* dbase = dxw + ((size_t)(b << 10) << 5);
  float a0 = 0.f, a1 = 0.f, a2 = 0.f, a3 = 0.f;
  int k = 0;
  for (; k + 4 <= cnt; k += 4) {
    int4 j4 = *(const int4*)(lst + k);
    a0 += dbase[(size_t)j4.x * 32 + f];
    a1 += dbase[(size_t)j4.y * 32 + f];
    a2 += dbase[(size_t)j4.z * 32 + f];
    a3 += dbase[(size_t)j4.w * 32 + f];
  }
  for (; k < cnt; ++k) a0 += dbase[(size_t)lst[k] * 32 + f];
  float acc = (a0 + a1) + (a2 + a3);
  acc += 2.0f * dxw[(size_t)node * 32 + f];
  float r = dis[node] * acc + bias[f];
  if (RELU) r = fmaxf(r, 0.f);
  out[(size_t)node * 32 + f] = r;
  if (SCORE) {
    float pv = p[f];
    float d = r * pv, pp = pv * pv;
#pragma unroll
    for (int o = 16; o; o >>= 1) { d += __shfl_xor(d, o, 32); pp += __shfl_xor(pp, o, 32); }
    if (f == 0) score[node] = tanhf(d / sqrtf(pp));
  }
}

// ---------------- top-k via packed u64-key bitonic sort --------------------
template<int M, int MPAD, int K>
__device__ void p_topk(int b, const float* __restrict__ score, int* __restrict__ perm,
                       float* __restrict__ vals, int* __restrict__ inv,
                       unsigned long long* skey) {
  int t = threadIdx.x;
#pragma unroll
  for (int e = 0; e < MPAD / 256; ++e) {
    int idx = e * 256 + t;
    unsigned int ordv;
    if (idx < M) {
      float v = score[b * M + idx];
      unsigned int u = __float_as_uint(v);
      if (u == 0x80000000u) u = 0u;
      ordv = (u & 0x80000000u) ? ~u : (u | 0x80000000u);
      inv[b * M + idx] = -1;
    } else {
      ordv = 0u;
    }
    skey[idx] = ((unsigned long long)(~ordv) << 32) | (unsigned int)idx;
  }
  __syncthreads();
  for (int k = 2; k <= MPAD; k <<= 1) {
    for (int j = k >> 1; j > 0; j >>= 1) {
#pragma unroll
      for (int e = 0; e < MPAD / 256; ++e) {
        int idx = e * 256 + t;
        int ixj = idx ^ j;
        if (ixj > idx) {
          unsigned long long a = skey[idx], c = skey[ixj];
          bool up = ((idx & k) == 0);
          if (up == (a > c)) { skey[idx] = c; skey[ixj] = a; }
        }
      }
      __syncthreads();
    }
  }
#pragma unroll
  for (int e = 0; e < MPAD / 256; ++e) {
    int idx = e * 256 + t;
    if (idx < K) {
      unsigned long long kk = skey[idx];
      unsigned int ord = ~(unsigned int)(kk >> 32);
      unsigned int u = (ord & 0x80000000u) ? (ord & 0x7FFFFFFFu) : ~ord;
      int src = (int)(kk & 0xFFFFFFFFull);
      perm[b * K + idx] = src;
      vals[b * K + idx] = __uint_as_float(u);
      inv[b * M + src] = idx;
    }
  }
}

// ---------------- A1 = augment(adj)[perm1,perm1] + dis1 + fused t1 ---------
__device__ void p_buildA1(const Params& P, int vb, SMem& sm) {
  int b = vb / 52, chunk = vb - b * 52;
  int t = threadIdx.x;
  if (t < KK1) sm.a1.sp[t] = P.perm1[b * KK1 + t];
  __syncthreads();
  for (int q = t; q < KK1 * 16; q += 256) {
    int i = q >> 4, w = q & 15;
    sm.a1.smT[w * KK1 + i] = P.mask[((size_t)(b * NN + sm.a1.sp[i])) * 16 + w];
  }
  __syncthreads();
  int wave = t >> 6, lane = t & 63;
  int i = chunk * 4 + wave;
  if (i < KK1) {
    unsigned long long r[16];
#pragma unroll
    for (int w = 0; w < 16; ++w) r[w] = sm.a1.smT[w * KK1 + i];
    float rowsum = 0.f;
    for (int j = lane; j < KK1; j += 64) {
      int cnt = 0;
#pragma unroll
      for (int w = 0; w < 16; ++w) cnt += __popcll(r[w] & sm.a1.smT[w * KK1 + j]);
      int pj = sm.a1.sp[j];
      float edge = (float)((r[pj >> 6] >> (pj & 63)) & 1ull);
      float v = (j == i) ? 0.f : ((float)cnt + 2.f * edge);
      P.A1[((size_t)(b * KK1) + i) * KK1 + j] = v;
      rowsum += v;
    }
#pragma unroll
    for (int o = 32; o; o >>= 1) rowsum += __shfl_xor(rowsum, o);
    float dis = rsqrtf(rowsum + 2.0f);
    if (lane == 0) P.dis1[b * KK1 + i] = dis;
    if (lane < 32) {                                   // fused t1 row
      int pi = sm.a1.sp[i];
      const float* hr = P.h0 + (size_t)(b * NN + pi) * 32;
      float s = 0.f;
#pragma unroll
      for (int k = 0; k < 32; ++k) s += hr[k] * P.Wd1[k * 32 + lane];
      P.t1[((size_t)(b * KK1) + i) * 32 + lane] = s * dis * P.vals1[b * KK1 + i];
    }
  }
}

// ---------------- dense GCN apply (+optional fused pool-2 score) -----------
template<bool RELU, bool SCORE>
__device__ void p_dense(const float* __restrict__ A, const float* __restrict__ tbuf,
                        const float* __restrict__ dis, const float* __restrict__ bias,
                        int M, float* __restrict__ out, float* __restrict__ score,
                        const float* __restrict__ p, int vb, SMem& sm) {
  int row = vb;
  int b = row / M, i = row - b * M;
  int tid = threadIdx.x, g = tid >> 5, f = tid & 31;
  const float* Ar = A + (size_t)row * M;
  const float* tb = tbuf + (size_t)b * M * 32;
  float acc = 0.f;
  for (int j = g; j < M; j += 8) acc += Ar[j] * tb[j * 32 + f];
  sm.ls[g][f] = acc;
  __syncthreads();
  if (tid < 32) {
    float s = 0.f;
#pragma unroll
    for (int q = 0; q < 8; ++q) s += sm.ls[q][tid];
    s += 2.0f * tb[i * 32 + tid];
    float r = dis[row] * s + bias[tid];
    if (RELU) r = fmaxf(r, 0.f);
    out[(size_t)row * 32 + tid] = r;
    if (SCORE) {
      float pv = p[tid];
      float d = r * pv, pp = pv * pv;
#pragma unroll
      for (int o = 16; o; o >>= 1) { d += __shfl_xor(d, o, 32); pp += __shfl_xor(pp, o, 32); }
      if (tid == 0) score[row] = tanhf(d / sqrtf(pp));
    }
  }
}

// ---------------- A2 = augment(A1)[perm2,perm2] + dis2 + fused t2 ----------
__device__ void p_buildA2(const Params& P, int vb, SMem& sm) {
  int row = vb;
  int b = row / KK2, i = row - b * KK2;
  int g = threadIdx.x >> 5, lane = threadIdx.x & 31;
  int pi = P.perm2[b * KK2 + i];
  const float* Ri = P.A1 + ((size_t)(b * KK1 + pi)) * KK1;
  float part = 0.f;
  for (int j = g; j < KK2; j += 8) {
    int pj = P.perm2[b * KK2 + j];
    const float* Rj = P.A1 + ((size_t)(b * KK1 + pj)) * KK1;
    float s = 0.f;
    for (int k = lane; k < KK1; k += 32) s += Ri[k] * Rj[k];
#pragma unroll
    for (int o = 16; o; o >>= 1) s += __shfl_xor(s, o, 32);
    float v = (i == j) ? 0.f : (s + 2.0f * Ri[pj]);
    if (lane == 0) {
      P.A2[((size_t)(b * KK2) + i) * KK2 + j] = v;
      part += v;
    }
  }
  if (lane == 0) sm.a2.gsum[g] = part;
  __syncthreads();
  if (threadIdx.x == 0) {
    float s = 0.f;
#pragma unroll
    for (int q = 0; q < 8; ++q) s += sm.a2.gsum[q];
    float d2 = rsqrtf(s + 2.0f);
    P.dis2[row] = d2;
    sm.a2.ds2 = d2;
  }
  __syncthreads();
  if (threadIdx.x < 32) {                              // fused t2 row
    const float* hr = P.h1 + (size_t)(b * KK1 + pi) * 32;
    float s = 0.f;
#pragma unroll
    for (int k = 0; k < 32; ++k) s += hr[k] * P.Wd2[k * 32 + threadIdx.x];
    P.t2[(size_t)row * 32 + threadIdx.x] = s * sm.a2.ds2 * P.vals2[row];
  }
}

// ---------------- t = dis * ((h + unpool(up)) @ W) -------------------------
__device__ void p_xw32u(const float* __restrict__ h, const float* __restrict__ up,
                        const int* __restrict__ inv, const float* __restrict__ W,
                        const float* __restrict__ dis, int M, int K,
                        float* __restrict__ out, int vb) {
  int idx = vb * 256 + threadIdx.x;
  int f = idx & 31; int node = idx >> 5;
  int b = node / M;
  int iv = inv[node];
  const float* xr = h + (size_t)node * 32;
  float s = 0.f;
  if (iv >= 0) {
    const float* ur = up + (size_t)(b * K + iv) * 32;
#pragma unroll
    for (int k = 0; k < 32; ++k) s += (xr[k] + ur[k]) * W[k * 32 + f];
  } else {
#pragma unroll
    for (int k = 0; k < 32; ++k) s += xr[k] * W[k * 32 + f];
  }
  out[idx] = s * dis[node];
}

// ---------------- batchnorm partial stats ----------------------------------
__device__ void p_bn(const Params& P, int vb, SMem& sm) {
  int t = threadIdx.x;
  int f = t & 31, g = t >> 5;
  int rowBase = vb * 128;
  float s = 0.f, sq = 0.f;
  for (int r = g; r < 128; r += 8) {
    float v = P.hfin[(size_t)(rowBase + r) * 32 + f];
    s += v; sq += v * v;
  }
  sm.bn.ls[g][f] = s; sm.bn.lq[g][f] = sq;
  __syncthreads();
  if (t < 32) {
    float S = 0.f, Q = 0.f;
#pragma unroll
    for (int i = 0; i < 8; ++i) { S += sm.bn.ls[i][t]; Q += sm.bn.lq[i][t]; }
    P.pacc[vb * 64 + t] = S;
    P.pacc[vb * 64 + 32 + t] = Q;
  }
}

// ---------------- BN + 3-layer MLP head ------------------------------------
__device__ void p_mlp(const Params& P, int vb, SMem& sm) {
  int t = threadIdx.x;
  ((float4*)sm.mlp.W1s)[t] = ((const float4*)P.W1)[t];
  ((float4*)sm.mlp.W2s)[t] = ((const float4*)P.W2)[t];
  if (t < 32) ((float4*)sm.mlp.W3s)[t] = ((const float4*)P.W3)[t];
  if (t < 32) { sm.mlp.b1s[t] = P.b1[t]; sm.mlp.b2s[t] = P.b2[t]; }
  if (t < 4) sm.mlp.b3s[t] = P.b3[t];
  if (t < 32) {
    float S = 0.f, Q = 0.f;
    for (int q = 0; q < 128; ++q) { S += P.pacc[q * 64 + t]; Q += P.pacc[q * 64 + 32 + t]; }
    const float inv = 1.0f / (float)(BB * NN);
    float m = S * inv;
    float v = Q * inv - m * m;
    float sc = P.gamma[t] * rsqrtf(v + 1e-5f);
    sm.mlp.scale[t] = sc;
    sm.mlp.shift[t] = P.beta[t] - m * sc;
  }
  __syncthreads();
  int node = vb * 256 + t;
  const float4* hr = (const float4*)(P.hfin + (size_t)node * 32);
  float hn[32];
#pragma unroll
  for (int i = 0; i < 8; ++i) {
    float4 xv = hr[i];
    hn[i * 4 + 0] = xv.x * sm.mlp.scale[i * 4 + 0] + sm.mlp.shift[i * 4 + 0];
    hn[i * 4 + 1] = xv.y * sm.mlp.scale[i * 4 + 1] + sm.mlp.shift[i * 4 + 1];
    hn[i * 4 + 2] = xv.z * sm.mlp.scale[i * 4 + 2] + sm.mlp.shift[i * 4 + 2];
    hn[i * 4 + 3] = xv.w * sm.mlp.scale[i * 4 + 3] + sm.mlp.shift[i * 4 + 3];
  }
  float r1[32];
#pragma unroll
  for (int f = 0; f < 32; ++f) r1[f] = sm.mlp.b1s[f];
#pragma unroll
  for (int k = 0; k < 32; ++k) {
    float a = hn[k];
#pragma unroll
    for (int f = 0; f < 32; ++f) r1[f] += a * sm.mlp.W1s[k * 32 + f];
  }
#pragma unroll
  for (int f = 0; f < 32; ++f) r1[f] = r1[f] > 0.f ? r1[f] : 0.01f * r1[f];
  float r2[32];
#pragma unroll
  for (int f = 0; f < 32; ++f) r2[f] = sm.mlp.b2s[f];
#pragma unroll
  for (int k = 0; k < 32; ++k) {
    float a = r1[k];
#pragma unroll
    for (int f = 0; f < 32; ++f) r2[f] += a * sm.mlp.W2s[k * 32 + f];
  }
#pragma unroll
  for (int f = 0; f < 32; ++f) r2[f] = r2[f] > 0.f ? r2[f] : 0.01f * r2[f];
  float r3[4];
#pragma unroll
  for (int c = 0; c < 4; ++c) r3[c] = sm.mlp.b3s[c];
#pragma unroll
  for (int k = 0; k < 32; ++k) {
    float a = r2[k];
#pragma unroll
    for (int c = 0; c < 4; ++c) r3[c] += a * sm.mlp.W3s[k * 4 + c];
  }
  float4 o;
  o.x = 1.0f / (1.0f + expf(-r3[0]));
  o.y = r3[1]; o.z = r3[2]; o.w = r3[3];
  ((float4*)P.out)[node] = o;
}

// ---------------- mega kernel: all 14 phases, 13 global barriers -----------
#define GS(vb, NVB) for (int vb = blockIdx.x; vb < (NVB); vb += nb)

__global__ __launch_bounds__(THREADS) void k_mega(Params P) {
  __shared__ SMem sm;
  const int nb = gridDim.x;

  GS(vb, VB_DEG) p_deg(P, vb);
  gsync(P.bar, 0, nb);
  GS(vb, VB_SPMM) p_spmm<true, true>(P.dxw, P.dis0, P.ncnt, P.nbr, P.bd0, P.h0, P.score1, P.p1, vb);
  gsync(P.bar, 1, nb);
  GS(vb, VB_TOPK) { p_topk<NN, 1024, KK1>(vb, P.score1, P.perm1, P.vals1, P.inv1, sm.skey); __syncthreads(); }
  gsync(P.bar, 2, nb);
  GS(vb, VB_A1) { p_buildA1(P, vb, sm); __syncthreads(); }
  gsync(P.bar, 3, nb);
  GS(vb, VB_DENSE1) { p_dense<true, true>(P.A1, P.t1, P.dis1, P.bd1, KK1, P.h1, P.score2, P.p2, vb, sm); __syncthreads(); }
  gsync(P.bar, 4, nb);
  GS(vb, VB_TOPK) { p_topk<KK1, 256, KK2>(vb, P.score2, P.perm2, P.vals2, P.inv2, sm.skey); __syncthreads(); }
  gsync(P.bar, 5, nb);
  GS(vb, VB_A2) { p_buildA2(P, vb, sm); __syncthreads(); }
  gsync(P.bar, 6, nb);
  GS(vb, VB_DENSE2) { p_dense<true, false>(P.A2, P.t2, P.dis2, P.bd2, KK2, P.h2, nullptr, nullptr, vb, sm); __syncthreads(); }
  gsync(P.bar, 7, nb);
  GS(vb, VB_XU1) p_xw32u(P.h1, P.h2, P.inv2, P.Wu0, P.dis1, KK1, KK2, P.t1, vb);
  gsync(P.bar, 8, nb);
  GS(vb, VB_DENSE1) { p_dense<true, false>(P.A1, P.t1, P.dis1, P.bu0, KK1, P.hu0, nullptr, nullptr, vb, sm); __syncthreads(); }
  gsync(P.bar, 9, nb);
  GS(vb, VB_XU0) p_xw32u(P.h0, P.hu0, P.inv1, P.Wu1, P.dis0, NN, KK1, P.dxw, vb);
  gsync(P.bar, 10, nb);
  GS(vb, VB_SPMM) p_spmm<false, false>(P.dxw, P.dis0, P.ncnt, P.nbr, P.bu1, P.hfin, nullptr, nullptr, vb);
  gsync(P.bar, 11, nb);
  GS(vb, VB_BN) { p_bn(P, vb, sm); __syncthreads(); }
  gsync(P.bar, 12, nb);
  GS(vb, VB_MLP) { p_mlp(P, vb, sm); __syncthreads(); }
}

__global__ void k_zero(unsigned* bar) {
  if (threadIdx.x < 16) bar[threadIdx.x] = 0u;
}

extern "C" void kernel_launch(void* const* d_in, const int* in_sizes, int n_in,
                              void* d_out, int out_size, void* d_ws, size_t ws_size,
                              hipStream_t stream) {
  Params P;
  P.x    = (const float*)d_in[0];
  P.adj  = (const float*)d_in[1];
  P.Wd0  = (const float*)d_in[2];
  P.bd0  = (const float*)d_in[3];
  P.Wd1  = (const float*)d_in[4];
  P.bd1  = (const float*)d_in[5];
  P.Wd2  = (const float*)d_in[6];
  P.bd2  = (const float*)d_in[7];
  P.Wu0  = (const float*)d_in[8];
  P.bu0  = (const float*)d_in[9];
  P.Wu1  = (const float*)d_in[10];
  P.bu1  = (const float*)d_in[11];
  P.p1   = (const float*)d_in[12];
  P.p2   = (const float*)d_in[13];
  P.gamma= (const float*)d_in[14];
  P.beta = (const float*)d_in[15];
  P.W1   = (const float*)d_in[16];
  P.b1   = (const float*)d_in[17];
  P.W2   = (const float*)d_in[18];
  P.b2   = (const float*)d_in[19];
  P.W3   = (const float*)d_in[20];
  P.b3   = (const float*)d_in[21];
  P.out  = (float*)d_out;

  char* w = (char*)d_ws;
  auto alloc = [&](size_t bytes) -> void* {
    void* p = (void*)w;
    w += (bytes + 255) & ~(size_t)255;
    return p;
  };
  P.dis0  = (float*)alloc(BB * NN * 4);
  P.ncnt  = (int*)alloc(BB * NN * 4);
  P.nbr   = (int*)alloc((size_t)BB * NN * CAP * 4);
  P.mask  = (unsigned long long*)alloc((size_t)BB * NN * 16 * 8);
  P.dxw   = (float*)alloc((size_t)BB * NN * 32 * 4);
  P.h0    = (float*)alloc((size_t)BB * NN * 32 * 4);
  P.score1= (float*)alloc(BB * NN * 4);
  P.perm1 = (int*)alloc(BB * KK1 * 4);
  P.vals1 = (float*)alloc(BB * KK1 * 4);
  P.inv1  = (int*)alloc(BB * NN * 4);
  P.A1    = (float*)alloc((size_t)BB * KK1 * KK1 * 4);
  P.dis1  = (float*)alloc(BB * KK1 * 4);
  P.t1    = (float*)alloc((size_t)BB * KK1 * 32 * 4);
  P.h1    = (float*)alloc((size_t)BB * KK1 * 32 * 4);
  P.score2= (float*)alloc(BB * KK1 * 4);
  P.perm2 = (int*)alloc(BB * KK2 * 4);
  P.vals2 = (float*)alloc(BB * KK2 * 4);
  P.inv2  = (int*)alloc(BB * KK1 * 4);
  P.A2    = (float*)alloc((size_t)BB * KK2 * KK2 * 4);
  P.dis2  = (float*)alloc(BB * KK2 * 4);
  P.t2    = (float*)alloc((size_t)BB * KK2 * 32 * 4);
  P.h2    = (float*)alloc((size_t)BB * KK2 * 32 * 4);
  P.hu0   = (float*)alloc((size_t)BB * KK1 * 32 * 4);
  P.hfin  = (float*)alloc((size_t)BB * NN * 32 * 4);
  P.pacc  = (float*)alloc(128 * 64 * 4);
  P.bar   = (unsigned*)alloc(16 * 4);

  // grid = exact co-resident capacity (persistent kernel, software barrier)
  static int s_blocks = 0;
  if (s_blocks == 0) {
    int maxB = 0;
    if (hipOccupancyMaxActiveBlocksPerMultiprocessor(&maxB, (const void*)k_mega,
                                                     THREADS, 0) != hipSuccess || maxB < 1)
      maxB = 1;
    int nCU = 256;
    hipDeviceProp_t prop;
    int dev = 0;
    if (hipGetDevice(&dev) == hipSuccess &&
        hipGetDeviceProperties(&prop, dev) == hipSuccess &&
        prop.multiProcessorCount > 0)
      nCU = prop.multiProcessorCount;
    long g = (long)maxB * nCU;
    if (g > 2048) g = 2048;
    s_blocks = (int)g;
  }

  k_zero<<<1, 64, 0, stream>>>(P.bar);
  k_mega<<<s_blocks, THREADS, 0, stream>>>(P);
}

// Round 2
// 306.081 us; speedup vs baseline: 3.8911x; 3.8911x over previous
//
#include <hip/hip_runtime.h>
#include <cmath>

#define BB 16
#define NN 1024
#define KK1 205
#define KK2 42
#define CAP 96
#define NPACC 2048   // spmm-final block count (one BN-partial slot each)

// ------- single adj pass: degree, bitmask, neighbor list, fused x@Wd0 ------
__global__ void k_deg_csr(const float* __restrict__ adj, const float* __restrict__ x,
                          const float* __restrict__ W,
                          float* __restrict__ dis0, int* __restrict__ ncnt,
                          int* __restrict__ nbr, unsigned long long* __restrict__ mask,
                          float* __restrict__ dxw) {
  int row = blockIdx.x * 4 + (threadIdx.x >> 6);   // one wave per row
  int lane = threadIdx.x & 63;
  const float* ar = adj + (size_t)row * NN;
  float v[16];
#pragma unroll
  for (int c = 0; c < 16; ++c) v[c] = ar[c * 64 + lane];   // 16 loads in flight
  int base = 0;
  int* nr = nbr + (size_t)row * CAP;
#pragma unroll
  for (int c = 0; c < 16; ++c) {
    unsigned long long m = __ballot(v[c] != 0.0f);
    if (lane == c) mask[(size_t)row * 16 + c] = m;
    if (v[c] != 0.0f) {
      int pos = base + __popcll(m & ((1ull << lane) - 1ull));
      if (pos < CAP) nr[pos] = c * 64 + lane;
    }
    base += __popcll(m);
  }
  float dis = rsqrtf((float)base + 2.0f);
  if (lane == 0) {
    ncnt[row] = base < CAP ? base : CAP;
    dis0[row] = dis;
  }
  if (lane < 32) {                                  // fused dxw = dis*(x@Wd0)
    float x0 = x[row * 3], x1 = x[row * 3 + 1], x2 = x[row * 3 + 2];
    float s = x0 * W[lane] + x1 * W[32 + lane] + x2 * W[64 + lane];
    dxw[(size_t)row * 32 + lane] = s * dis;
  }
}

// ------- sparse GCN apply (+opt fused pool score / +opt BN partials) -------
template<bool RELU, bool SCORE, bool BNSTATS>
__global__ void k_spmm(const float* __restrict__ dxw, const float* __restrict__ dis,
                       const int* __restrict__ ncnt, const int* __restrict__ nbr,
                       const float* __restrict__ bias, float* __restrict__ out,
                       float* __restrict__ score, const float* __restrict__ p,
                       float* __restrict__ pacc) {
  int tid = threadIdx.x;
  int g = tid >> 5, f = tid & 31;
  int node = blockIdx.x * 8 + g;                  // node = b*NN + i
  int b = node >> 10;
  int cnt = ncnt[node];
  const int* lst = nbr + (size_t)node * CAP;      // 384B-aligned rows
  const float* dbase = dxw + ((size_t)(b << 10) << 5);
  float a0 = 0.f, a1 = 0.f, a2 = 0.f, a3 = 0.f;
  int k = 0;
  for (; k + 4 <= cnt; k += 4) {
    int4 j4 = *(const int4*)(lst + k);
    a0 += dbase[(size_t)j4.x * 32 + f];
    a1 += dbase[(size_t)j4.y * 32 + f];
    a2 += dbase[(size_t)j4.z * 32 + f];
    a3 += dbase[(size_t)j4.w * 32 + f];
  }
  for (; k < cnt; ++k) a0 += dbase[(size_t)lst[k] * 32 + f];
  float acc = (a0 + a1) + (a2 + a3);
  acc += 2.0f * dxw[(size_t)node * 32 + f];
  float r = dis[node] * acc + bias[f];
  if (RELU) r = fmaxf(r, 0.f);
  out[(size_t)node * 32 + f] = r;
  if (SCORE) {                                    // score[node] = tanh(h·p/||p||)
    float pv = p[f];
    float d = r * pv, pp = pv * pv;
#pragma unroll
    for (int o = 16; o; o >>= 1) { d += __shfl_xor(d, o, 32); pp += __shfl_xor(pp, o, 32); }
    if (f == 0) score[node] = tanhf(d / sqrtf(pp));
  }
  if (BNSTATS) {                                  // per-block BN partials
    __shared__ float bs[8][32], bq[8][32];
    bs[g][f] = r; bq[g][f] = r * r;
    __syncthreads();
    if (tid < 32) {
      float S = 0.f, Q = 0.f;
#pragma unroll
      for (int q = 0; q < 8; ++q) { S += bs[q][tid]; Q += bq[q][tid]; }
      pacc[blockIdx.x * 64 + tid] = S;
      pacc[blockIdx.x * 64 + 32 + tid] = Q;
    }
  }
}

// ---------------- top-k via packed u64-key bitonic sort + inverse map ------
// key = (~ord(v) << 32) | idx, ascending  ==> value desc, index asc on ties.
template<int M, int MPAD, int K, int NT>
__global__ void k_topk(const float* __restrict__ score, int* __restrict__ perm,
                       float* __restrict__ vals, int* __restrict__ inv) {
  __shared__ unsigned long long skey[MPAD];
  int b = blockIdx.x, t = threadIdx.x;
  for (int idx = t; idx < MPAD; idx += NT) {
    unsigned int ordv;
    if (idx < M) {
      float v = score[b * M + idx];
      unsigned int u = __float_as_uint(v);
      if (u == 0x80000000u) u = 0u;               // normalize -0.0
      ordv = (u & 0x80000000u) ? ~u : (u | 0x80000000u);
      inv[b * M + idx] = -1;
    } else {
      ordv = 0u;                                   // sorts last
    }
    skey[idx] = ((unsigned long long)(~ordv) << 32) | (unsigned int)idx;
  }
  __syncthreads();
  for (int k = 2; k <= MPAD; k <<= 1) {
    for (int j = k >> 1; j > 0; j >>= 1) {
      for (int idx = t; idx < MPAD; idx += NT) {
        int ixj = idx ^ j;
        if (ixj > idx) {
          unsigned long long a = skey[idx], c = skey[ixj];
          bool up = ((idx & k) == 0);
          if (up == (a > c)) { skey[idx] = c; skey[ixj] = a; }
        }
      }
      __syncthreads();
    }
  }
  for (int idx = t; idx < MPAD; idx += NT) {
    if (idx < K) {
      unsigned long long kk = skey[idx];
      unsigned int ord = ~(unsigned int)(kk >> 32);
      unsigned int u = (ord & 0x80000000u) ? (ord & 0x7FFFFFFFu) : ~ord;
      int src = (int)(kk & 0xFFFFFFFFull);
      perm[b * K + idx] = src;
      vals[b * K + idx] = __uint_as_float(u);
      inv[b * M + src] = idx;
    }
  }
}

// ------- A1 = augment(adj)[perm1,perm1] + dis1 + fused t1 ------------------
// t1[i] = dis1[i]*vals1[i]*(h0[perm1[i]] @ Wd1)
__global__ void k_buildA1(const unsigned long long* __restrict__ mask,
                          const int* __restrict__ perm1,
                          const float* __restrict__ h0, const float* __restrict__ Wd1,
                          const float* __restrict__ vals1,
                          float* __restrict__ A1, float* __restrict__ dis1,
                          float* __restrict__ t1) {
  __shared__ unsigned long long smT[16 * KK1];   // transposed: smT[w*KK1 + j]
  __shared__ int sp[KK1];
  int blk = blockIdx.x;
  int b = blk / 52, chunk = blk - b * 52;
  int t = threadIdx.x;
  if (t < KK1) sp[t] = perm1[b * KK1 + t];
  __syncthreads();
  for (int q = t; q < KK1 * 16; q += 256) {
    int i = q >> 4, w = q & 15;
    smT[w * KK1 + i] = mask[((size_t)(b * NN + sp[i])) * 16 + w];
  }
  __syncthreads();
  int wave = t >> 6, lane = t & 63;
  int i = chunk * 4 + wave;
  if (i < KK1) {
    unsigned long long r[16];
#pragma unroll
    for (int w = 0; w < 16; ++w) r[w] = smT[w * KK1 + i];
    float rowsum = 0.f;
    for (int j = lane; j < KK1; j += 64) {
      int cnt = 0;
#pragma unroll
      for (int w = 0; w < 16; ++w) cnt += __popcll(r[w] & smT[w * KK1 + j]);
      int pj = sp[j];
      float edge = (float)((r[pj >> 6] >> (pj & 63)) & 1ull);
      float v = (j == i) ? 0.f : ((float)cnt + 2.f * edge);
      A1[((size_t)(b * KK1) + i) * KK1 + j] = v;
      rowsum += v;
    }
#pragma unroll
    for (int o = 32; o; o >>= 1) rowsum += __shfl_xor(rowsum, o);
    float dis = rsqrtf(rowsum + 2.0f);             // all lanes hold it
    if (lane == 0) dis1[b * KK1 + i] = dis;
    if (lane < 32) {                               // fused t1 row
      const float* hr = h0 + (size_t)(b * NN + sp[i]) * 32;
      float s = 0.f;
#pragma unroll
      for (int k = 0; k < 32; ++k) s += hr[k] * Wd1[k * 32 + lane];
      t1[((size_t)(b * KK1) + i) * 32 + lane] = s * dis * vals1[b * KK1 + i];
    }
  }
}

// ------- dense GCN apply: one block per row (+opt fused pool-2 score) ------
template<bool RELU, bool SCORE>
__global__ __launch_bounds__(256) void k_dense_apply(
    const float* __restrict__ A, const float* __restrict__ tbuf,
    const float* __restrict__ dis, const float* __restrict__ bias,
    int M, float* __restrict__ out, float* __restrict__ score,
    const float* __restrict__ p) {
  int row = blockIdx.x;
  int b = row / M, i = row - b * M;
  int tid = threadIdx.x;
  int g = tid >> 5, f = tid & 31;
  const float* Ar = A + (size_t)row * M;
  const float* tb = tbuf + (size_t)b * M * 32;
  float acc = 0.f;
  for (int j = g; j < M; j += 8)
    acc += Ar[j] * tb[j * 32 + f];
  __shared__ float ls[8][32];
  ls[g][f] = acc;
  __syncthreads();
  if (tid < 32) {
    float s = 0.f;
#pragma unroll
    for (int q = 0; q < 8; ++q) s += ls[q][tid];
    s += 2.0f * tb[i * 32 + tid];
    float r = dis[row] * s + bias[tid];
    if (RELU) r = fmaxf(r, 0.f);
    out[(size_t)row * 32 + tid] = r;
    if (SCORE) {
      float pv = p[tid];
      float d = r * pv, pp = pv * pv;
#pragma unroll
      for (int o = 16; o; o >>= 1) { d += __shfl_xor(d, o, 32); pp += __shfl_xor(pp, o, 32); }
      if (tid == 0) score[row] = tanhf(d / sqrtf(pp));
    }
  }
}

// ------- A2 = augment(A1)[perm2,perm2] + dis2 + fused t2 -------------------
__global__ void k_buildA2(const float* __restrict__ A1, const int* __restrict__ perm2,
                          const float* __restrict__ h1, const float* __restrict__ Wd2,
                          const float* __restrict__ vals2,
                          float* __restrict__ A2, float* __restrict__ dis2,
                          float* __restrict__ t2) {
  __shared__ float gsum[8];
  __shared__ float ds2s;
  int row = blockIdx.x;                            // b*KK2 + i
  int b = row / KK2, i = row - b * KK2;
  int g = threadIdx.x >> 5, lane = threadIdx.x & 31;
  int pi = perm2[b * KK2 + i];
  const float* Ri = A1 + ((size_t)(b * KK1 + pi)) * KK1;
  float part = 0.f;
  for (int j = g; j < KK2; j += 8) {
    int pj = perm2[b * KK2 + j];
    const float* Rj = A1 + ((size_t)(b * KK1 + pj)) * KK1;
    float s = 0.f;
    for (int k = lane; k < KK1; k += 32) s += Ri[k] * Rj[k];
#pragma unroll
    for (int o = 16; o; o >>= 1) s += __shfl_xor(s, o, 32);
    float v = (i == j) ? 0.f : (s + 2.0f * Ri[pj]);
    if (lane == 0) {
      A2[((size_t)(b * KK2) + i) * KK2 + j] = v;
      part += v;
    }
  }
  if (lane == 0) gsum[g] = part;
  __syncthreads();
  if (threadIdx.x == 0) {
    float s = 0.f;
#pragma unroll
    for (int q = 0; q < 8; ++q) s += gsum[q];
    float d2 = rsqrtf(s + 2.0f);
    dis2[row] = d2;
    ds2s = d2;
  }
  __syncthreads();
  if (threadIdx.x < 32) {                          // fused t2 row
    const float* hr = h1 + (size_t)(b * KK1 + pi) * 32;
    float s = 0.f;
#pragma unroll
    for (int k = 0; k < 32; ++k) s += hr[k] * Wd2[k * 32 + threadIdx.x];
    t2[(size_t)row * 32 + threadIdx.x] = s * ds2s * vals2[row];
  }
}

// ------- t = dis * ((h + unpool(up)) @ W)  (scatter-add fused via inv) -----
__global__ void k_xw32u(const float* __restrict__ h, const float* __restrict__ up,
                        const int* __restrict__ inv, const float* __restrict__ W,
                        const float* __restrict__ dis, int M, int K,
                        float* __restrict__ out) {
  int idx = blockIdx.x * 256 + threadIdx.x;       // rows*32
  int f = idx & 31; int node = idx >> 5;          // node = b*M + i
  int b = node / M;
  int iv = inv[node];
  const float* xr = h + (size_t)node * 32;
  float s = 0.f;
  if (iv >= 0) {
    const float* ur = up + (size_t)(b * K + iv) * 32;
#pragma unroll
    for (int k = 0; k < 32; ++k) s += (xr[k] + ur[k]) * W[k * 32 + f];
  } else {
#pragma unroll
    for (int k = 0; k < 32; ++k) s += xr[k] * W[k * 32 + f];
  }
  out[idx] = s * dis[node];
}

// ------- BN (reduce NPACC partial slots) + 3-layer MLP head ----------------
__global__ __launch_bounds__(64) void k_mlp(
    const float* __restrict__ h, const float* __restrict__ pacc,
    const float* __restrict__ gamma, const float* __restrict__ beta,
    const float* __restrict__ W1, const float* __restrict__ b1,
    const float* __restrict__ W2, const float* __restrict__ b2,
    const float* __restrict__ W3, const float* __restrict__ b3,
    float* __restrict__ out) {
  __shared__ float sW1[1024], sW2[1024], sW3[128];
  __shared__ float sb1[32], sb2[32], sb3[4], sscale[32], sshift[32];
  __shared__ float red[64];
  int t = threadIdx.x;
  {
    const float4* W1v = (const float4*)W1; float4* d1 = (float4*)sW1;
#pragma unroll
    for (int i = 0; i < 4; ++i) d1[t + i * 64] = W1v[t + i * 64];
    const float4* W2v = (const float4*)W2; float4* d2 = (float4*)sW2;
#pragma unroll
    for (int i = 0; i < 4; ++i) d2[t + i * 64] = W2v[t + i * 64];
    if (t < 32) ((float4*)sW3)[t] = ((const float4*)W3)[t];
    if (t < 32) { sb1[t] = b1[t]; sb2[t] = b2[t]; }
    if (t < 4) sb3[t] = b3[t];
    // all 64 threads reduce the NPACC partial slots (col t: 0..31=S, 32..63=Q)
    float a0 = 0.f, a1 = 0.f, a2 = 0.f, a3 = 0.f,
          a4 = 0.f, a5 = 0.f, a6 = 0.f, a7 = 0.f;
    for (int q = 0; q < NPACC; q += 8) {
      a0 += pacc[(q + 0) * 64 + t]; a1 += pacc[(q + 1) * 64 + t];
      a2 += pacc[(q + 2) * 64 + t]; a3 += pacc[(q + 3) * 64 + t];
      a4 += pacc[(q + 4) * 64 + t]; a5 += pacc[(q + 5) * 64 + t];
      a6 += pacc[(q + 6) * 64 + t]; a7 += pacc[(q + 7) * 64 + t];
    }
    red[t] = ((a0 + a1) + (a2 + a3)) + ((a4 + a5) + (a6 + a7));
  }
  __syncthreads();
  if (t < 32) {
    const float inv = 1.0f / (float)(BB * NN);
    float m = red[t] * inv;
    float v = red[32 + t] * inv - m * m;
    float sc = gamma[t] * rsqrtf(v + 1e-5f);
    sscale[t] = sc;
    sshift[t] = beta[t] - m * sc;
  }
  __syncthreads();
  int node = blockIdx.x * 64 + t;
  const float4* hr = (const float4*)(h + (size_t)node * 32);
  float hn[32];
#pragma unroll
  for (int i = 0; i < 8; ++i) {
    float4 x = hr[i];
    hn[i * 4 + 0] = x.x * sscale[i * 4 + 0] + sshift[i * 4 + 0];
    hn[i * 4 + 1] = x.y * sscale[i * 4 + 1] + sshift[i * 4 + 1];
    hn[i * 4 + 2] = x.z * sscale[i * 4 + 2] + sshift[i * 4 + 2];
    hn[i * 4 + 3] = x.w * sscale[i * 4 + 3] + sshift[i * 4 + 3];
  }
  float r1[32];
#pragma unroll
  for (int f = 0; f < 32; ++f) r1[f] = sb1[f];
#pragma unroll
  for (int k = 0; k < 32; ++k) {
    float a = hn[k];
#pragma unroll
    for (int f = 0; f < 32; ++f) r1[f] += a * sW1[k * 32 + f];
  }
#pragma unroll
  for (int f = 0; f < 32; ++f) r1[f] = r1[f] > 0.f ? r1[f] : 0.01f * r1[f];
  float r2[32];
#pragma unroll
  for (int f = 0; f < 32; ++f) r2[f] = sb2[f];
#pragma unroll
  for (int k = 0; k < 32; ++k) {
    float a = r1[k];
#pragma unroll
    for (int f = 0; f < 32; ++f) r2[f] += a * sW2[k * 32 + f];
  }
#pragma unroll
  for (int f = 0; f < 32; ++f) r2[f] = r2[f] > 0.f ? r2[f] : 0.01f * r2[f];
  float r3[4];
#pragma unroll
  for (int c = 0; c < 4; ++c) r3[c] = sb3[c];
#pragma unroll
  for (int k = 0; k < 32; ++k) {
    float a = r2[k];
#pragma unroll
    for (int c = 0; c < 4; ++c) r3[c] += a * sW3[k * 4 + c];
  }
  float4 o;
  o.x = 1.0f / (1.0f + expf(-r3[0]));
  o.y = r3[1]; o.z = r3[2]; o.w = r3[3];
  ((float4*)out)[node] = o;
}

extern "C" void kernel_launch(void* const* d_in, const int* in_sizes, int n_in,
                              void* d_out, int out_size, void* d_ws, size_t ws_size,
                              hipStream_t stream) {
  const float* x    = (const float*)d_in[0];
  const float* adj  = (const float*)d_in[1];
  const float* Wd0  = (const float*)d_in[2];
  const float* bd0  = (const float*)d_in[3];
  const float* Wd1  = (const float*)d_in[4];
  const float* bd1  = (const float*)d_in[5];
  const float* Wd2  = (const float*)d_in[6];
  const float* bd2  = (const float*)d_in[7];
  const float* Wu0  = (const float*)d_in[8];
  const float* bu0  = (const float*)d_in[9];
  const float* Wu1  = (const float*)d_in[10];
  const float* bu1  = (const float*)d_in[11];
  const float* p1   = (const float*)d_in[12];
  const float* p2   = (const float*)d_in[13];
  const float* gamma= (const float*)d_in[14];
  const float* beta = (const float*)d_in[15];
  const float* W1   = (const float*)d_in[16];
  const float* b1   = (const float*)d_in[17];
  const float* W2   = (const float*)d_in[18];
  const float* b2   = (const float*)d_in[19];
  const float* W3   = (const float*)d_in[20];
  const float* b3   = (const float*)d_in[21];
  float* out = (float*)d_out;

  char* w = (char*)d_ws;
  auto alloc = [&](size_t bytes) -> void* {
    void* p = (void*)w;
    w += (bytes + 255) & ~(size_t)255;
    return p;
  };
  float* dis0 = (float*)alloc(BB * NN * 4);
  int*   ncnt = (int*)alloc(BB * NN * 4);
  int*   nbr  = (int*)alloc((size_t)BB * NN * CAP * 4);
  unsigned long long* mask = (unsigned long long*)alloc((size_t)BB * NN * 16 * 8);
  float* dxw  = (float*)alloc((size_t)BB * NN * 32 * 4);
  float* h0   = (float*)alloc((size_t)BB * NN * 32 * 4);
  float* score1 = (float*)alloc(BB * NN * 4);
  int*   perm1= (int*)alloc(BB * KK1 * 4);
  float* vals1= (float*)alloc(BB * KK1 * 4);
  int*   inv1 = (int*)alloc(BB * NN * 4);
  float* A1   = (float*)alloc((size_t)BB * KK1 * KK1 * 4);
  float* dis1 = (float*)alloc(BB * KK1 * 4);
  float* t1   = (float*)alloc((size_t)BB * KK1 * 32 * 4);
  float* h1   = (float*)alloc((size_t)BB * KK1 * 32 * 4);
  float* score2 = (float*)alloc(BB * KK1 * 4);
  int*   perm2= (int*)alloc(BB * KK2 * 4);
  float* vals2= (float*)alloc(BB * KK2 * 4);
  int*   inv2 = (int*)alloc(BB * KK1 * 4);
  float* A2   = (float*)alloc((size_t)BB * KK2 * KK2 * 4);
  float* dis2 = (float*)alloc(BB * KK2 * 4);
  float* t2   = (float*)alloc((size_t)BB * KK2 * 32 * 4);
  float* h2   = (float*)alloc((size_t)BB * KK2 * 32 * 4);
  float* hu0  = (float*)alloc((size_t)BB * KK1 * 32 * 4);
  float* hfin = (float*)alloc((size_t)BB * NN * 32 * 4);
  float* pacc = (float*)alloc((size_t)NPACC * 64 * 4);

  const int TOT_N32  = BB * NN * 32;     // 524288
  const int TOT_K132 = BB * KK1 * 32;    // 104960

  // 1) adj pass: degree + bitmask + CSR + fused x@Wd0
  k_deg_csr<<<BB * NN / 4, 256, 0, stream>>>(adj, x, Wd0, dis0, ncnt, nbr, mask, dxw);
  // 2) GCN0 apply (+fused pool-1 score)
  k_spmm<true, true, false><<<BB * NN / 8, 256, 0, stream>>>(
      dxw, dis0, ncnt, nbr, bd0, h0, score1, p1, nullptr);
  // 3) top-k pool 1 (+inv1)
  k_topk<NN, 1024, KK1, 1024><<<BB, 1024, 0, stream>>>(score1, perm1, vals1, inv1);
  // 4) A1 (+dis1, +fused t1 = dis1*vals1*(h0[perm1]@Wd1))
  k_buildA1<<<BB * 52, 256, 0, stream>>>(mask, perm1, h0, Wd1, vals1, A1, dis1, t1);
  // 5) GCN1 apply (+fused pool-2 score)
  k_dense_apply<true, true><<<BB * KK1, 256, 0, stream>>>(
      A1, t1, dis1, bd1, KK1, h1, score2, p2);
  // 6) top-k pool 2 (+inv2)
  k_topk<KK1, 256, KK2, 256><<<BB, 256, 0, stream>>>(score2, perm2, vals2, inv2);
  // 7) A2 (+dis2, +fused t2)
  k_buildA2<<<BB * KK2, 256, 0, stream>>>(A1, perm2, h1, Wd2, vals2, A2, dis2, t2);
  // 8) GCN2 apply
  k_dense_apply<true, false><<<BB * KK2, 256, 0, stream>>>(
      A2, t2, dis2, bd2, KK2, h2, nullptr, nullptr);
  // 9) up-GCN level-1 (unpool fused via inv2)
  k_xw32u<<<TOT_K132 / 256, 256, 0, stream>>>(h1, h2, inv2, Wu0, dis1, KK1, KK2, t1);
  k_dense_apply<true, false><<<BB * KK1, 256, 0, stream>>>(
      A1, t1, dis1, bu0, KK1, hu0, nullptr, nullptr);
  // 10) final GCN level-0 (unpool fused via inv1, sparse, no relu, +BN partials)
  k_xw32u<<<TOT_N32 / 256, 256, 0, stream>>>(h0, hu0, inv1, Wu1, dis0, NN, KK1, dxw);
  k_spmm<false, false, true><<<BB * NN / 8, 256, 0, stream>>>(
      dxw, dis0, ncnt, nbr, bu1, hfin, nullptr, nullptr, pacc);
  // 11) fused BN-reduce + MLP head
  k_mlp<<<BB * NN / 64, 64, 0, stream>>>(hfin, pacc, gamma, beta,
                                         W1, b1, W2, b2, W3, b3, out);
}